// Round 1
// baseline (12883.315 us; speedup 1.0000x reference)
//
#include <hip/hip_runtime.h>
#include <hip/hip_fp16.h>

#define DD 1024
#define TSTEPS 1024
#define BATCH 8

typedef _Float16 half8 __attribute__((ext_vector_type(8)));
typedef float floatx4 __attribute__((ext_vector_type(4)));

// ---- d_out float offsets ----
#define OUT_OFF   0
#define LOGH_OFF  8388608
#define SIGNH_OFF 16785408
#define HLIN_OFF  25182208

// ---- ws byte offsets ----
#define WS_SCALES  0          // float[2]
#define WS_SUMSQ   64         // float[2][8]
#define WS_CNTS    128        // int[2][8]   (spectral barriers)
#define WS_CNTSUB  256        // int[1024][8] (recurrence barrier sub-counters) -> [256,33024)
#define WS_COMM    33280      // ushort[2][8][1024] f16 h double-buffer -> [33280,66048)
#define WS_SPECVEC 66048      // float[2][2][1024] power-iter ping-pong
#define WS_MEMSET  33024      // zero [0, 33024)

__device__ __forceinline__ void waitcnt_vm0() { asm volatile("s_waitcnt vmcnt(0)" ::: "memory"); }
__device__ __forceinline__ int aload_i(int* p) { return __hip_atomic_load(p, __ATOMIC_RELAXED, __HIP_MEMORY_SCOPE_AGENT); }
__device__ __forceinline__ float aload_f(float* p) { return __hip_atomic_load(p, __ATOMIC_RELAXED, __HIP_MEMORY_SCOPE_AGENT); }
__device__ __forceinline__ unsigned aload_u(unsigned* p) { return __hip_atomic_load(p, __ATOMIC_RELAXED, __HIP_MEMORY_SCOPE_AGENT); }
__device__ __forceinline__ void astore_f(float* p, float v) { __hip_atomic_store(p, v, __ATOMIC_RELAXED, __HIP_MEMORY_SCOPE_AGENT); }
__device__ __forceinline__ void astore_us(unsigned short* p, unsigned short v) { __hip_atomic_store(p, v, __ATOMIC_RELAXED, __HIP_MEMORY_SCOPE_AGENT); }
__device__ __forceinline__ void aadd_i(int* p, int v) { (void)__hip_atomic_fetch_add(p, v, __ATOMIC_RELAXED, __HIP_MEMORY_SCOPE_AGENT); }

// ============================================================================
// Spectral norm: 3-step power iteration for both matrices concurrently.
// 64 WGs per matrix; phase outputs through agent-coherent ws buffers + spin barriers.
// sigma = ||W v||^2 / (||W v|| + 1e-8) from the last matvec's sumsq.
// ============================================================================
__global__ __launch_bounds__(256) void spectral_kernel(
    const float* __restrict__ Wh, const float* __restrict__ Wd,
    const float* __restrict__ uh, const float* __restrict__ ud,
    unsigned char* __restrict__ ws) {
  const int g  = blockIdx.x >> 6;
  const int wg = blockIdx.x & 63;
  const int tid = threadIdx.x;
  const float* W  = g ? Wd : Wh;
  const float* u0 = g ? ud : uh;
  float* scales = (float*)(ws + WS_SCALES);
  float* sumsq  = (float*)(ws + WS_SUMSQ) + g*8;
  int*   cnt    = (int*)(ws + WS_CNTS) + g*8;
  float* ubuf   = (float*)(ws + WS_SPECVEC) + g*2048;
  float* vbuf   = ubuf + 1024;

  __shared__ float xs[1024];
  __shared__ float tileW[256*17];
  __shared__ float red[16*17];

  // phase 0: ||u0||^2, redundantly per WG (deterministic identical result)
  float ss = 0.f;
  for (int i2 = tid; i2 < 1024; i2 += 256) { float x = u0[i2]; ss += x*x; }
  #pragma unroll
  for (int off = 1; off < 64; off <<= 1) ss += __shfl_xor(ss, off);
  if ((tid & 63) == 0) red[tid >> 6] = ss;
  __syncthreads();
  float inv_prev = 1.f/(sqrtf(red[0]+red[1]+red[2]+red[3]) + 1e-8f);
  __syncthreads();

  for (int p = 1; p <= 6; ++p) {
    const int colmv = p & 1;            // odd: y = W^T x ; even: y = W x
    float* dst  = colmv ? vbuf : ubuf;
    float* srcw = colmv ? ubuf : vbuf;  // ws source (p>=2)
    float part = 0.f;
    if (colmv) {
      const int jb = wg*16;
      const int jl = tid & 15, is = tid >> 4;
      float acc = 0.f;
      for (int i0 = 0; i0 < 1024; i0 += 256) {
        __syncthreads();
        float xv = (p == 1) ? u0[i0 + tid] : aload_f(srcw + i0 + tid);
        xs[tid] = xv * inv_prev;
        const float* wr = W + (size_t)(i0 + tid)*DD + jb;
        float4 a = *(const float4*)(wr + 0);
        float4 bq = *(const float4*)(wr + 4);
        float4 cq = *(const float4*)(wr + 8);
        float4 dq = *(const float4*)(wr + 12);
        float* tr = tileW + tid*17;
        tr[0]=a.x; tr[1]=a.y; tr[2]=a.z; tr[3]=a.w;
        tr[4]=bq.x; tr[5]=bq.y; tr[6]=bq.z; tr[7]=bq.w;
        tr[8]=cq.x; tr[9]=cq.y; tr[10]=cq.z; tr[11]=cq.w;
        tr[12]=dq.x; tr[13]=dq.y; tr[14]=dq.z; tr[15]=dq.w;
        __syncthreads();
        #pragma unroll 4
        for (int ii = 0; ii < 16; ++ii)
          acc += tileW[(is*16 + ii)*17 + jl] * xs[is*16 + ii];
      }
      __syncthreads();
      red[is*17 + jl] = acc;
      __syncthreads();
      if (tid < 16) {
        float y = 0.f;
        #pragma unroll
        for (int k = 0; k < 16; ++k) y += red[k*17 + tid];
        astore_f(dst + jb + tid, y);
        part = y*y;
      }
    } else {
      const int ib = wg*16;
      for (int i2 = tid; i2 < 1024; i2 += 256) xs[i2] = aload_f(srcw + i2) * inv_prev;
      __syncthreads();
      const int r = tid >> 4, s = tid & 15;
      const float* wr = W + (size_t)(ib + r)*DD;
      float acc = 0.f;
      #pragma unroll 8
      for (int jj = 0; jj < 64; ++jj) {
        int j = s + (jj << 4);
        acc += wr[j] * xs[j];
      }
      #pragma unroll
      for (int off = 1; off < 16; off <<= 1) acc += __shfl_xor(acc, off);
      __syncthreads();
      if (s == 0) red[r] = acc;
      __syncthreads();
      if (tid < 16) {
        float y = red[tid];
        astore_f(dst + ib + tid, y);
        part = y*y;
      }
    }
    // accumulate output sumsq and barrier
    #pragma unroll
    for (int off = 1; off < 16; off <<= 1) part += __shfl_xor(part, off);
    if (tid == 0) atomicAdd(sumsq + p, part);
    waitcnt_vm0();
    __syncthreads();
    if (tid == 0) {
      aadd_i(cnt + p, 1);
      while (aload_i(cnt + p) < 64) __builtin_amdgcn_s_sleep(1);
    }
    __syncthreads();
    float stot = aload_f(sumsq + p);
    inv_prev = 1.f/(sqrtf(stot) + 1e-8f);
    __syncthreads();
  }
  if (wg == 0 && tid == 0) {
    float n2 = aload_f(sumsq + 6);
    float nn = sqrtf(n2);
    float sigma = (nn*nn)/(nn + 1e-8f);
    scales[g] = 0.99f/(sigma + 1e-8f);
  }
}

// ============================================================================
// f16 MFMA GEMM: C[m][n] = sum_k A[m][k]*B[n][k] (+bias). Dual-B fused variant
// shares the A tile. M=8192, N=K=1024. 64x64 tile, BK=32, 4 waves @ 32x32.
// ============================================================================
__device__ __forceinline__ half8 cvt8(const float* p) {
  float4 lo = *(const float4*)p;
  float4 hi = *(const float4*)(p+4);
  half8 h;
  h[0]=(_Float16)lo.x; h[1]=(_Float16)lo.y; h[2]=(_Float16)lo.z; h[3]=(_Float16)lo.w;
  h[4]=(_Float16)hi.x; h[5]=(_Float16)hi.y; h[6]=(_Float16)hi.z; h[7]=(_Float16)hi.w;
  return h;
}

__global__ __launch_bounds__(256) void gemm_f16(
    const float* __restrict__ A,
    const float* __restrict__ B1, const float* __restrict__ B2,
    const float* __restrict__ bias1, const float* __restrict__ bias2,
    float* __restrict__ C1, float* __restrict__ C2) {
  const int n0 = blockIdx.x * 64;
  const int m0 = blockIdx.y * 64;
  const int tid = threadIdx.x;
  const int wave = tid >> 6, lane = tid & 63;
  const int quad = lane >> 4, l16 = lane & 15;
  const bool dual = (B2 != nullptr);
  __shared__ _Float16 As[64*40];
  __shared__ _Float16 Bs1[64*40];
  __shared__ _Float16 Bs2[64*40];
  floatx4 zero = {0.f,0.f,0.f,0.f};
  floatx4 acc1[2][2] = {{zero,zero},{zero,zero}};
  floatx4 acc2[2][2] = {{zero,zero},{zero,zero}};
  const int srow = tid >> 2;
  const int sseg = (tid & 3) * 8;
  const int mb = (wave >> 1)*32, nb = (wave & 1)*32;
  for (int k0 = 0; k0 < 1024; k0 += 32) {
    __syncthreads();
    *(half8*)&As[srow*40 + sseg]  = cvt8(A  + (size_t)(m0+srow)*DD + k0 + sseg);
    *(half8*)&Bs1[srow*40 + sseg] = cvt8(B1 + (size_t)(n0+srow)*DD + k0 + sseg);
    if (dual) *(half8*)&Bs2[srow*40 + sseg] = cvt8(B2 + (size_t)(n0+srow)*DD + k0 + sseg);
    __syncthreads();
    half8 a0 = *(const half8*)&As[(mb + l16)*40 + quad*8];
    half8 a1 = *(const half8*)&As[(mb + 16 + l16)*40 + quad*8];
    half8 b0 = *(const half8*)&Bs1[(nb + l16)*40 + quad*8];
    half8 b1 = *(const half8*)&Bs1[(nb + 16 + l16)*40 + quad*8];
    acc1[0][0] = __builtin_amdgcn_mfma_f32_16x16x32_f16(a0, b0, acc1[0][0], 0,0,0);
    acc1[0][1] = __builtin_amdgcn_mfma_f32_16x16x32_f16(a0, b1, acc1[0][1], 0,0,0);
    acc1[1][0] = __builtin_amdgcn_mfma_f32_16x16x32_f16(a1, b0, acc1[1][0], 0,0,0);
    acc1[1][1] = __builtin_amdgcn_mfma_f32_16x16x32_f16(a1, b1, acc1[1][1], 0,0,0);
    if (dual) {
      half8 c0 = *(const half8*)&Bs2[(nb + l16)*40 + quad*8];
      half8 c1 = *(const half8*)&Bs2[(nb + 16 + l16)*40 + quad*8];
      acc2[0][0] = __builtin_amdgcn_mfma_f32_16x16x32_f16(a0, c0, acc2[0][0], 0,0,0);
      acc2[0][1] = __builtin_amdgcn_mfma_f32_16x16x32_f16(a0, c1, acc2[0][1], 0,0,0);
      acc2[1][0] = __builtin_amdgcn_mfma_f32_16x16x32_f16(a1, c0, acc2[1][0], 0,0,0);
      acc2[1][1] = __builtin_amdgcn_mfma_f32_16x16x32_f16(a1, c1, acc2[1][1], 0,0,0);
    }
  }
  #pragma unroll
  for (int in = 0; in < 2; ++in) {
    const int n = n0 + nb + in*16 + l16;
    const float bv1 = bias1 ? bias1[n] : 0.f;
    const float bv2 = (dual && bias2) ? bias2[n] : 0.f;
    #pragma unroll
    for (int im = 0; im < 2; ++im) {
      const int mrow = m0 + mb + im*16 + quad*4;
      floatx4 c = acc1[im][in];
      #pragma unroll
      for (int r2 = 0; r2 < 4; ++r2) C1[(size_t)(mrow + r2)*DD + n] = c[r2] + bv1;
      if (dual) {
        floatx4 c2 = acc2[im][in];
        #pragma unroll
        for (int r2 = 0; r2 < 4; ++r2) C2[(size_t)(mrow + r2)*DD + n] = c2[r2] + bv2;
      }
    }
  }
}

// ============================================================================
// Persistent recurrence: 256 WGs (1/CU) x 256 thr. WG owns 4 hidden rows.
// Scaled R_h/R_delta rows live in registers as static MFMA A-frags (M-tile:
// m0-3 = v rows, m4-7 = delta rows, m8-15 pad). Each wave covers K-slice 256.
// h broadcast per step via agent-scope f16 comm double-buffer + split-counter
// spin barrier. h_prev for own rows kept in registers (fp32).
// ============================================================================
__global__ __launch_bounds__(256, 1) void recurrence_kernel(
    const float* __restrict__ Rh_raw, const float* __restrict__ Rd_raw,
    const float* __restrict__ logh0, const float* __restrict__ signh0,
    float* __restrict__ dout, unsigned char* __restrict__ ws) {
  const int wg = blockIdx.x;
  const int i0 = wg * 4;
  const int tid = threadIdx.x;
  const int wave = tid >> 6;
  const int lane = tid & 63;
  const int quad = lane >> 4;
  const int l16 = lane & 15;

  float* out_ax = dout + OUT_OFF;     // ax aliased into 'out' region
  float* hlin   = dout + HLIN_OFF;    // ad aliased here (consumed per step)
  float* logh   = dout + LOGH_OFF;
  float* signh  = dout + SIGNH_OFF;
  const float* scales = (const float*)(ws + WS_SCALES);
  int* cnt_sub = (int*)(ws + WS_CNTSUB);
  unsigned short* comm = (unsigned short*)(ws + WS_COMM);

  __shared__ _Float16 hf[16*1032];
  __shared__ floatx4 scratch[4][64];

  // zero pad batch rows 8..15 of hf (never re-written)
  for (int idx = tid; idx < 8*1032; idx += 256) hf[8*1032 + idx] = (_Float16)0.f;

  // static A-fragments: weights * spectral scale, f16
  const float sh = scales[0], sd = scales[1];
  half8 afrag[8];
  {
    const int m = l16;
    const float* wsrc = (m < 4) ? (Rh_raw + (size_t)(i0+m)*DD)
                     : ((m < 8) ? (Rd_raw + (size_t)(i0 + m - 4)*DD) : nullptr);
    const float sc = (m < 4) ? sh : sd;
    for (int ks = 0; ks < 8; ++ks) {
      half8 h;
      const int kb = wave*256 + ks*32 + quad*8;
      #pragma unroll
      for (int j = 0; j < 8; ++j) {
        float v = wsrc ? wsrc[kb + j] * sc : 0.f;
        h[j] = (_Float16)v;
      }
      afrag[ks] = h;
    }
  }

  const int i  = i0 + wave;   // this wave's hidden row
  const int bn = l16;         // batch (valid < 8) for epilogue lanes
  float hp = 0.f;
  if (quad == 0 && bn < 8) {
    hp = signh0[bn*DD + i] * expf(logh0[bn*DD + i]);
  }

  const int s_n = tid >> 5;          // staging: batch row
  const int s_k = (tid & 31) * 32;   // staging: 32-f16 chunk

  __syncthreads();

  for (int t = 0; t < TSTEPS; ++t) {
    // prefetch ax/ad (independent of barrier)
    float axv = 0.f, adv = 0.f;
    if (quad == 0 && bn < 8) {
      axv = out_ax[(size_t)(t*8 + bn)*DD + i];
      adv = hlin[(size_t)(t*8 + bn)*DD + i];   // ad aliased; overwritten below
    }
    float vsum = 0.f, dsum = 0.f;
    if (t > 0) {
      // barrier: wait for all 256 WGs to finish step t-1 (8 parallel pollers)
      if (tid < 8) {
        while (aload_i(cnt_sub + (t-1)*8 + tid) < 32) __builtin_amdgcn_s_sleep(1);
      }
      __syncthreads();
      // stage comm[(t-1)&1] -> LDS hf
      {
        unsigned* src = (unsigned*)(comm + ((t-1)&1)*8192 + s_n*1024 + s_k);
        unsigned vals[16];
        #pragma unroll
        for (int q = 0; q < 16; ++q) vals[q] = aload_u(src + q);
        _Float16* dstp = hf + s_n*1032 + s_k;
        #pragma unroll
        for (int q = 0; q < 4; ++q) {
          uint4 u; u.x = vals[q*4+0]; u.y = vals[q*4+1]; u.z = vals[q*4+2]; u.w = vals[q*4+3];
          *(uint4*)(dstp + q*8) = u;
        }
      }
      __syncthreads();
      // MFMA over this wave's K-slice
      floatx4 acc = {0.f,0.f,0.f,0.f};
      const int kw = wave*256;
      #pragma unroll
      for (int ks = 0; ks < 8; ++ks) {
        half8 bfrag = *(const half8*)&hf[l16*1032 + kw + ks*32 + quad*8];
        acc = __builtin_amdgcn_mfma_f32_16x16x32_f16(afrag[ks], bfrag, acc, 0, 0, 0);
      }
      scratch[wave][lane] = acc;
      __syncthreads();
      if (lane < 16) {
        // C layout: element C[m][n] at lane (m>>2)*16+n, reg m&3.
        // v row m=wave -> lanes 0..15 reg=wave; d row m=4+wave -> lanes 16..31 reg=wave
        #pragma unroll
        for (int w2 = 0; w2 < 4; ++w2) {
          vsum += scratch[w2][lane][wave];
          dsum += scratch[w2][16 + lane][wave];
        }
      }
    }
    // epilogue: one (row i, batch bn) per active lane
    if (quad == 0 && bn < 8) {
      float v  = axv + vsum;
      float dd = adv + dsum;
      float cand  = tanhf(v);
      float delta = 1.f/(1.f + expf(-dd));
      float hn = (1.f - delta)*hp + delta*cand;
      hp = hn;
      const size_t oidx = (size_t)(t*8 + bn)*DD + i;
      hlin[oidx] = hn;
      logh[(size_t)((t+1)*8 + bn)*DD + i] = logf(fabsf(hn) + 1e-12f);
      signh[(size_t)((t+1)*8 + bn)*DD + i] = (hn >= 0.f) ? 1.f : -1.f;
      __half hh = __float2half(hn);
      astore_us(comm + (t&1)*8192 + bn*1024 + i, __half_as_ushort(hh));
    }
    // arrive
    waitcnt_vm0();
    __syncthreads();
    if (tid == 0) aadd_i(cnt_sub + t*8 + (wg & 7), 1);
  }
}

// ============================================================================
// out = softmax(h over groups of 32) * silu(h @ W_out^T). Y is pre-stored in
// the out region; rewritten element-wise.
// ============================================================================
__global__ __launch_bounds__(256) void out_epilogue(
    const float* __restrict__ hlin, float* __restrict__ y_out) {
  const int row = blockIdx.x;          // t*8+b
  const int tid = threadIdx.x;
  const float* h = hlin + (size_t)row*DD;
  float* yo = y_out + (size_t)row*DD;
  const int e = tid*4;
  float4 hv = *(const float4*)(h + e);
  float4 yv = *(const float4*)(yo + e);
  float m = fmaxf(fmaxf(hv.x,hv.y), fmaxf(hv.z,hv.w));
  #pragma unroll
  for (int off = 1; off < 8; off <<= 1) m = fmaxf(m, __shfl_xor(m, off));
  float e0 = expf(hv.x - m), e1 = expf(hv.y - m), e2 = expf(hv.z - m), e3 = expf(hv.w - m);
  float s = e0+e1+e2+e3;
  #pragma unroll
  for (int off = 1; off < 8; off <<= 1) s += __shfl_xor(s, off);
  float inv = 1.f/s;
  float4 o;
  o.x = e0*inv * (yv.x/(1.f+expf(-yv.x)));
  o.y = e1*inv * (yv.y/(1.f+expf(-yv.y)));
  o.z = e2*inv * (yv.z/(1.f+expf(-yv.z)));
  o.w = e3*inv * (yv.w/(1.f+expf(-yv.w)));
  *(float4*)(yo + e) = o;
}

__global__ __launch_bounds__(256) void init_rows(
    const float* __restrict__ lh0, const float* __restrict__ sh0, float* __restrict__ dout) {
  int idx = blockIdx.x*256 + threadIdx.x;   // 8192
  dout[LOGH_OFF + idx]  = lh0[idx];
  dout[SIGNH_OFF + idx] = sh0[idx];
}

extern "C" void kernel_launch(void* const* d_in, const int* in_sizes, int n_in,
                              void* d_out, int out_size, void* d_ws, size_t ws_size,
                              hipStream_t stream) {
  const float* x      = (const float*)d_in[0];
  const float* logh0  = (const float*)d_in[1];
  const float* signh0 = (const float*)d_in[2];
  const float* Rh_raw = (const float*)d_in[3];
  const float* Rx     = (const float*)d_in[4];
  const float* Rd_raw = (const float*)d_in[5];
  const float* Wdelta = (const float*)d_in[6];
  const float* Wout   = (const float*)d_in[7];
  const float* bvec   = (const float*)d_in[8];
  const float* bdelta = (const float*)d_in[9];
  const float* uh     = (const float*)d_in[10];
  const float* ud     = (const float*)d_in[11];
  float* out = (float*)d_out;
  unsigned char* ws = (unsigned char*)d_ws;

  hipMemsetAsync(ws, 0, WS_MEMSET, stream);
  spectral_kernel<<<128, 256, 0, stream>>>(Rh_raw, Rd_raw, uh, ud, ws);
  // ax -> out region, ad -> h_lin region (dead-aliased scratch)
  gemm_f16<<<dim3(16,128), 256, 0, stream>>>(x, Rx, Wdelta, bvec, bdelta,
                                             out + OUT_OFF, out + HLIN_OFF);
  init_rows<<<32, 256, 0, stream>>>(logh0, signh0, out);
  recurrence_kernel<<<256, 256, 0, stream>>>(Rh_raw, Rd_raw, logh0, signh0, out, ws);
  // Y = h_lin @ W_out^T -> out region (ax dead)
  gemm_f16<<<dim3(16,128), 256, 0, stream>>>(out + HLIN_OFF, Wout, nullptr, nullptr, nullptr,
                                             out + OUT_OFF, nullptr);
  out_epilogue<<<8192, 256, 0, stream>>>(out + HLIN_OFF, out + OUT_OFF);
}

// Round 2
// 7228.053 us; speedup vs baseline: 1.7824x; 1.7824x over previous
//
#include <hip/hip_runtime.h>
#include <hip/hip_fp16.h>

#define DD 1024
#define TSTEPS 1024
#define BATCH 8
#define NWG 64
#define ROWS 16

typedef _Float16 half8 __attribute__((ext_vector_type(8)));
typedef float floatx4 __attribute__((ext_vector_type(4)));

// ---- d_out float offsets ----
#define OUT_OFF   0
#define LOGH_OFF  8388608
#define SIGNH_OFF 16785408
#define HLIN_OFF  25182208

// ---- ws byte offsets ----
#define WS_SCALES  0          // float[2]
#define WS_SUMSQ   64         // float[2][8]
#define WS_CNTS    128        // int[2][8]   (spectral barriers)
#define WS_SPECVEC 256        // float[2][2][1024] power-iter ping-pong -> [256,16640)
#define WS_COMM    16640      // unsigned[2][8][1024] tagged f16 h double-buffer -> [16640,82176)

__device__ __forceinline__ int aload_i(int* p) { return __hip_atomic_load(p, __ATOMIC_RELAXED, __HIP_MEMORY_SCOPE_AGENT); }
__device__ __forceinline__ float aload_f(float* p) { return __hip_atomic_load(p, __ATOMIC_RELAXED, __HIP_MEMORY_SCOPE_AGENT); }
__device__ __forceinline__ unsigned aload_u(unsigned* p) { return __hip_atomic_load(p, __ATOMIC_RELAXED, __HIP_MEMORY_SCOPE_AGENT); }
__device__ __forceinline__ void astore_f(float* p, float v) { __hip_atomic_store(p, v, __ATOMIC_RELAXED, __HIP_MEMORY_SCOPE_AGENT); }
__device__ __forceinline__ void astore_u(unsigned* p, unsigned v) { __hip_atomic_store(p, v, __ATOMIC_RELAXED, __HIP_MEMORY_SCOPE_AGENT); }
__device__ __forceinline__ void aadd_i(int* p, int v) { (void)__hip_atomic_fetch_add(p, v, __ATOMIC_RELAXED, __HIP_MEMORY_SCOPE_AGENT); }
__device__ __forceinline__ void waitcnt_vm0() { asm volatile("s_waitcnt vmcnt(0)" ::: "memory"); }
__device__ __forceinline__ unsigned pack2(unsigned lo, unsigned hi) { return (lo & 0xffffu) | (hi << 16); }

// ============================================================================
// Spectral norm: 3-step power iteration for both matrices concurrently.
// 64 WGs per matrix; phase outputs through agent-coherent ws buffers + spin barriers.
// sigma = ||W v||^2 / (||W v|| + 1e-8) from the last matvec's sumsq.
// ============================================================================
__global__ __launch_bounds__(256) void spectral_kernel(
    const float* __restrict__ Wh, const float* __restrict__ Wd,
    const float* __restrict__ uh, const float* __restrict__ ud,
    unsigned char* __restrict__ ws) {
  const int g  = blockIdx.x >> 6;
  const int wg = blockIdx.x & 63;
  const int tid = threadIdx.x;
  const float* W  = g ? Wd : Wh;
  const float* u0 = g ? ud : uh;
  float* scales = (float*)(ws + WS_SCALES);
  float* sumsq  = (float*)(ws + WS_SUMSQ) + g*8;
  int*   cnt    = (int*)(ws + WS_CNTS) + g*8;
  float* ubuf   = (float*)(ws + WS_SPECVEC) + g*2048;
  float* vbuf   = ubuf + 1024;

  __shared__ float xs[1024];
  __shared__ float tileW[256*17];
  __shared__ float red[16*17];

  // phase 0: ||u0||^2, redundantly per WG (deterministic identical result)
  float ss = 0.f;
  for (int i2 = tid; i2 < 1024; i2 += 256) { float x = u0[i2]; ss += x*x; }
  #pragma unroll
  for (int off = 1; off < 64; off <<= 1) ss += __shfl_xor(ss, off);
  if ((tid & 63) == 0) red[tid >> 6] = ss;
  __syncthreads();
  float inv_prev = 1.f/(sqrtf(red[0]+red[1]+red[2]+red[3]) + 1e-8f);
  __syncthreads();

  for (int p = 1; p <= 6; ++p) {
    const int colmv = p & 1;            // odd: y = W^T x ; even: y = W x
    float* dst  = colmv ? vbuf : ubuf;
    float* srcw = colmv ? ubuf : vbuf;  // ws source (p>=2)
    float part = 0.f;
    if (colmv) {
      const int jb = wg*16;
      const int jl = tid & 15, is = tid >> 4;
      float acc = 0.f;
      for (int i0 = 0; i0 < 1024; i0 += 256) {
        __syncthreads();
        float xv = (p == 1) ? u0[i0 + tid] : aload_f(srcw + i0 + tid);
        xs[tid] = xv * inv_prev;
        const float* wr = W + (size_t)(i0 + tid)*DD + jb;
        float4 a = *(const float4*)(wr + 0);
        float4 bq = *(const float4*)(wr + 4);
        float4 cq = *(const float4*)(wr + 8);
        float4 dq = *(const float4*)(wr + 12);
        float* tr = tileW + tid*17;
        tr[0]=a.x; tr[1]=a.y; tr[2]=a.z; tr[3]=a.w;
        tr[4]=bq.x; tr[5]=bq.y; tr[6]=bq.z; tr[7]=bq.w;
        tr[8]=cq.x; tr[9]=cq.y; tr[10]=cq.z; tr[11]=cq.w;
        tr[12]=dq.x; tr[13]=dq.y; tr[14]=dq.z; tr[15]=dq.w;
        __syncthreads();
        #pragma unroll 4
        for (int ii = 0; ii < 16; ++ii)
          acc += tileW[(is*16 + ii)*17 + jl] * xs[is*16 + ii];
      }
      __syncthreads();
      red[is*17 + jl] = acc;
      __syncthreads();
      if (tid < 16) {
        float y = 0.f;
        #pragma unroll
        for (int k = 0; k < 16; ++k) y += red[k*17 + tid];
        astore_f(dst + jb + tid, y);
        part = y*y;
      }
    } else {
      const int ib = wg*16;
      for (int i2 = tid; i2 < 1024; i2 += 256) xs[i2] = aload_f(srcw + i2) * inv_prev;
      __syncthreads();
      const int r = tid >> 4, s = tid & 15;
      const float* wr = W + (size_t)(ib + r)*DD;
      float acc = 0.f;
      #pragma unroll 8
      for (int jj = 0; jj < 64; ++jj) {
        int j = s + (jj << 4);
        acc += wr[j] * xs[j];
      }
      #pragma unroll
      for (int off = 1; off < 16; off <<= 1) acc += __shfl_xor(acc, off);
      __syncthreads();
      if (s == 0) red[r] = acc;
      __syncthreads();
      if (tid < 16) {
        float y = red[tid];
        astore_f(dst + ib + tid, y);
        part = y*y;
      }
    }
    // accumulate output sumsq and barrier
    #pragma unroll
    for (int off = 1; off < 16; off <<= 1) part += __shfl_xor(part, off);
    if (tid == 0) atomicAdd(sumsq + p, part);
    waitcnt_vm0();
    __syncthreads();
    if (tid == 0) {
      aadd_i(cnt + p, 1);
      while (aload_i(cnt + p) < 64) __builtin_amdgcn_s_sleep(1);
    }
    __syncthreads();
    float stot = aload_f(sumsq + p);
    inv_prev = 1.f/(sqrtf(stot) + 1e-8f);
    __syncthreads();
  }
  if (wg == 0 && tid == 0) {
    float n2 = aload_f(sumsq + 6);
    float nn = sqrtf(n2);
    float sigma = (nn*nn)/(nn + 1e-8f);
    scales[g] = 0.99f/(sigma + 1e-8f);
  }
}

// ============================================================================
// f16 MFMA GEMM: C[m][n] = sum_k A[m][k]*B[n][k] (+bias). Dual-B fused variant
// shares the A tile. M=8192, N=K=1024. 64x64 tile, BK=32, 4 waves @ 32x32.
// ============================================================================
__device__ __forceinline__ half8 cvt8(const float* p) {
  float4 lo = *(const float4*)p;
  float4 hi = *(const float4*)(p+4);
  half8 h;
  h[0]=(_Float16)lo.x; h[1]=(_Float16)lo.y; h[2]=(_Float16)lo.z; h[3]=(_Float16)lo.w;
  h[4]=(_Float16)hi.x; h[5]=(_Float16)hi.y; h[6]=(_Float16)hi.z; h[7]=(_Float16)hi.w;
  return h;
}

__global__ __launch_bounds__(256) void gemm_f16(
    const float* __restrict__ A,
    const float* __restrict__ B1, const float* __restrict__ B2,
    const float* __restrict__ bias1, const float* __restrict__ bias2,
    float* __restrict__ C1, float* __restrict__ C2) {
  const int n0 = blockIdx.x * 64;
  const int m0 = blockIdx.y * 64;
  const int tid = threadIdx.x;
  const int wave = tid >> 6, lane = tid & 63;
  const int quad = lane >> 4, l16 = lane & 15;
  const bool dual = (B2 != nullptr);
  __shared__ _Float16 As[64*40];
  __shared__ _Float16 Bs1[64*40];
  __shared__ _Float16 Bs2[64*40];
  floatx4 zero = {0.f,0.f,0.f,0.f};
  floatx4 acc1[2][2] = {{zero,zero},{zero,zero}};
  floatx4 acc2[2][2] = {{zero,zero},{zero,zero}};
  const int srow = tid >> 2;
  const int sseg = (tid & 3) * 8;
  const int mb = (wave >> 1)*32, nb = (wave & 1)*32;
  for (int k0 = 0; k0 < 1024; k0 += 32) {
    __syncthreads();
    *(half8*)&As[srow*40 + sseg]  = cvt8(A  + (size_t)(m0+srow)*DD + k0 + sseg);
    *(half8*)&Bs1[srow*40 + sseg] = cvt8(B1 + (size_t)(n0+srow)*DD + k0 + sseg);
    if (dual) *(half8*)&Bs2[srow*40 + sseg] = cvt8(B2 + (size_t)(n0+srow)*DD + k0 + sseg);
    __syncthreads();
    half8 a0 = *(const half8*)&As[(mb + l16)*40 + quad*8];
    half8 a1 = *(const half8*)&As[(mb + 16 + l16)*40 + quad*8];
    half8 b0 = *(const half8*)&Bs1[(nb + l16)*40 + quad*8];
    half8 b1 = *(const half8*)&Bs1[(nb + 16 + l16)*40 + quad*8];
    acc1[0][0] = __builtin_amdgcn_mfma_f32_16x16x32_f16(a0, b0, acc1[0][0], 0,0,0);
    acc1[0][1] = __builtin_amdgcn_mfma_f32_16x16x32_f16(a0, b1, acc1[0][1], 0,0,0);
    acc1[1][0] = __builtin_amdgcn_mfma_f32_16x16x32_f16(a1, b0, acc1[1][0], 0,0,0);
    acc1[1][1] = __builtin_amdgcn_mfma_f32_16x16x32_f16(a1, b1, acc1[1][1], 0,0,0);
    if (dual) {
      half8 c0 = *(const half8*)&Bs2[(nb + l16)*40 + quad*8];
      half8 c1 = *(const half8*)&Bs2[(nb + 16 + l16)*40 + quad*8];
      acc2[0][0] = __builtin_amdgcn_mfma_f32_16x16x32_f16(a0, c0, acc2[0][0], 0,0,0);
      acc2[0][1] = __builtin_amdgcn_mfma_f32_16x16x32_f16(a0, c1, acc2[0][1], 0,0,0);
      acc2[1][0] = __builtin_amdgcn_mfma_f32_16x16x32_f16(a1, c0, acc2[1][0], 0,0,0);
      acc2[1][1] = __builtin_amdgcn_mfma_f32_16x16x32_f16(a1, c1, acc2[1][1], 0,0,0);
    }
  }
  #pragma unroll
  for (int in = 0; in < 2; ++in) {
    const int n = n0 + nb + in*16 + l16;
    const float bv1 = bias1 ? bias1[n] : 0.f;
    const float bv2 = (dual && bias2) ? bias2[n] : 0.f;
    #pragma unroll
    for (int im = 0; im < 2; ++im) {
      const int mrow = m0 + mb + im*16 + quad*4;
      floatx4 c = acc1[im][in];
      #pragma unroll
      for (int r2 = 0; r2 < 4; ++r2) C1[(size_t)(mrow + r2)*DD + n] = c[r2] + bv1;
      if (dual) {
        floatx4 c2 = acc2[im][in];
        #pragma unroll
        for (int r2 = 0; r2 < 4; ++r2) C2[(size_t)(mrow + r2)*DD + n] = c2[r2] + bv2;
      }
    }
  }
}

// ============================================================================
// Persistent recurrence, DATAFLOW-SYNCED (no atomics, no counters):
// 64 WGs x 256 thr; WG owns 16 hidden rows. Scaled R_h/R_delta rows live in
// registers as static MFMA A-frags (16 rows x K-slice 256 per wave, both
// matrices = 128 f16 = 64 VGPR/thread). h broadcast per step via tagged
// 32-bit words (tag<<16 | f16) in an agent-coherent double buffer: consumers
// poll the words themselves — the all-to-all read IS the barrier.
// ============================================================================
__global__ __launch_bounds__(256, 1) void recurrence_kernel(
    const float* __restrict__ Rh_raw, const float* __restrict__ Rd_raw,
    const float* __restrict__ logh0, const float* __restrict__ signh0,
    float* __restrict__ dout, unsigned char* __restrict__ ws) {
  const int wg = blockIdx.x;
  const int i0 = wg * ROWS;
  const int tid = threadIdx.x;
  const int wave = tid >> 6, lane = tid & 63;
  const int quad = lane >> 4, l16 = lane & 15;

  float* out_ax = dout + OUT_OFF;     // ax aliased into 'out' region
  float* hlin   = dout + HLIN_OFF;    // ad aliased here (consumed per step)
  float* logh   = dout + LOGH_OFF;
  float* signh  = dout + SIGNH_OFF;
  const float* scales = (const float*)(ws + WS_SCALES);
  unsigned* comm = (unsigned*)(ws + WS_COMM);

  __shared__ _Float16 hf[16*1032];
  __shared__ floatx4 scr_v[4][64];
  __shared__ floatx4 scr_d[4][64];

  // zero pad batch rows 8..15 of hf (never re-written)
  for (int idx = tid; idx < 8*1032; idx += 256) hf[8*1032 + idx] = (_Float16)0.f;

  // static A-fragments: weights * spectral scale, f16. A[m=l16][k=quad*8+j].
  const float sh = scales[0], sd = scales[1];
  half8 afv[8], afd[8];
  {
    const float* rv = Rh_raw + (size_t)(i0 + l16)*DD;
    const float* rd = Rd_raw + (size_t)(i0 + l16)*DD;
    for (int ks = 0; ks < 8; ++ks) {
      const int kb = wave*256 + ks*32 + quad*8;
      half8 hv, hd;
      #pragma unroll
      for (int j = 0; j < 8; ++j) {
        hv[j] = (_Float16)(rv[kb + j] * sh);
        hd[j] = (_Float16)(rd[kb + j] * sd);
      }
      afv[ks] = hv; afd[ks] = hd;
    }
  }

  // epilogue identity: tid<128 -> (row em, batch eb)
  const int em = tid & 15;
  const int eb = tid >> 4;
  const bool ep = (tid < 128);
  const int ei = i0 + em;
  float hp = 0.f;
  if (ep) hp = signh0[eb*DD + ei] * expf(logh0[eb*DD + ei]);

  // poll identity: words [pb*1024 + pk0, +32)
  const int pb = tid >> 5;
  const int pk0 = (tid & 31) * 32;

  __syncthreads();

  for (int t = 0; t < TSTEPS; ++t) {
    // prefetch ax/ad (HBM latency hidden under the poll)
    float axv = 0.f, adv = 0.f;
    if (ep) {
      axv = out_ax[(size_t)(t*8 + eb)*DD + ei];
      adv = hlin[(size_t)(t*8 + eb)*DD + ei];   // ad aliased; overwritten below
    }
    float vsum = 0.f, dsum = 0.f;
    if (t > 0) {
      // poll tagged words of step t-1; stage to LDS as groups complete
      unsigned* src = comm + ((t-1)&1)*8192 + pb*1024 + pk0;
      const unsigned tagv = (unsigned)t;
      unsigned done = 0;
      while (done != 0xFFu) {
        #pragma unroll
        for (int v2 = 0; v2 < 8; ++v2) {
          if (done & (1u << v2)) continue;
          unsigned u0 = aload_u(src + v2*4 + 0);
          unsigned u1 = aload_u(src + v2*4 + 1);
          unsigned u2 = aload_u(src + v2*4 + 2);
          unsigned u3 = aload_u(src + v2*4 + 3);
          if ((u0>>16)==tagv && (u1>>16)==tagv && (u2>>16)==tagv && (u3>>16)==tagv) {
            uint2 w; w.x = pack2(u0,u1); w.y = pack2(u2,u3);
            *(uint2*)&hf[pb*1032 + pk0 + v2*4] = w;
            done |= 1u << v2;
          }
        }
      }
      __syncthreads();
      // MFMA over this wave's K-slice (both matrices share the B-frag)
      floatx4 av = {0.f,0.f,0.f,0.f}, ad2 = {0.f,0.f,0.f,0.f};
      const int kw = wave*256;
      #pragma unroll
      for (int ks = 0; ks < 8; ++ks) {
        half8 bfrag = *(const half8*)&hf[l16*1032 + kw + ks*32 + quad*8];
        av  = __builtin_amdgcn_mfma_f32_16x16x32_f16(afv[ks], bfrag, av,  0, 0, 0);
        ad2 = __builtin_amdgcn_mfma_f32_16x16x32_f16(afd[ks], bfrag, ad2, 0, 0, 0);
      }
      scr_v[wave][lane] = av;
      scr_d[wave][lane] = ad2;
      __syncthreads();
      if (ep) {
        // C[m][n]: lane=(m>>2)*16+n, reg=m&3
        const int rl = ((em >> 2) << 4) + eb;
        const int rr = em & 3;
        #pragma unroll
        for (int w2 = 0; w2 < 4; ++w2) {
          vsum += scr_v[w2][rl][rr];
          dsum += scr_d[w2][rl][rr];
        }
      }
    }
    // epilogue: one (row ei, batch eb) per thread (tid<128)
    if (ep) {
      float v  = axv + vsum;
      float dd = adv + dsum;
      float cand  = tanhf(v);
      float delta = 1.f/(1.f + expf(-dd));
      float hn = (1.f - delta)*hp + delta*cand;
      hp = hn;
      // tagged comm word FIRST (critical path), outputs after
      unsigned hb = (unsigned)__half_as_ushort(__float2half(hn));
      astore_u(comm + (t&1)*8192 + eb*1024 + ei, ((unsigned)(t+1) << 16) | hb);
      const size_t oidx = (size_t)(t*8 + eb)*DD + ei;
      hlin[oidx] = hn;
      logh[(size_t)((t+1)*8 + eb)*DD + ei] = logf(fabsf(hn) + 1e-12f);
      signh[(size_t)((t+1)*8 + eb)*DD + ei] = (hn >= 0.f) ? 1.f : -1.f;
    }
  }
}

// ============================================================================
// out = softmax(h over groups of 32) * silu(h @ W_out^T). Y is pre-stored in
// the out region; rewritten element-wise.
// ============================================================================
__global__ __launch_bounds__(256) void out_epilogue(
    const float* __restrict__ hlin, float* __restrict__ y_out) {
  const int row = blockIdx.x;          // t*8+b
  const int tid = threadIdx.x;
  const float* h = hlin + (size_t)row*DD;
  float* yo = y_out + (size_t)row*DD;
  const int e = tid*4;
  float4 hv = *(const float4*)(h + e);
  float4 yv = *(const float4*)(yo + e);
  float m = fmaxf(fmaxf(hv.x,hv.y), fmaxf(hv.z,hv.w));
  #pragma unroll
  for (int off = 1; off < 8; off <<= 1) m = fmaxf(m, __shfl_xor(m, off));
  float e0 = expf(hv.x - m), e1 = expf(hv.y - m), e2 = expf(hv.z - m), e3 = expf(hv.w - m);
  float s = e0+e1+e2+e3;
  #pragma unroll
  for (int off = 1; off < 8; off <<= 1) s += __shfl_xor(s, off);
  float inv = 1.f/s;
  float4 o;
  o.x = e0*inv * (yv.x/(1.f+expf(-yv.x)));
  o.y = e1*inv * (yv.y/(1.f+expf(-yv.y)));
  o.z = e2*inv * (yv.z/(1.f+expf(-yv.z)));
  o.w = e3*inv * (yv.w/(1.f+expf(-yv.w)));
  *(float4*)(yo + e) = o;
}

__global__ __launch_bounds__(256) void init_rows(
    const float* __restrict__ lh0, const float* __restrict__ sh0, float* __restrict__ dout) {
  int idx = blockIdx.x*256 + threadIdx.x;   // 8192
  dout[LOGH_OFF + idx]  = lh0[idx];
  dout[SIGNH_OFF + idx] = sh0[idx];
}

extern "C" void kernel_launch(void* const* d_in, const int* in_sizes, int n_in,
                              void* d_out, int out_size, void* d_ws, size_t ws_size,
                              hipStream_t stream) {
  const float* x      = (const float*)d_in[0];
  const float* logh0  = (const float*)d_in[1];
  const float* signh0 = (const float*)d_in[2];
  const float* Rh_raw = (const float*)d_in[3];
  const float* Rx     = (const float*)d_in[4];
  const float* Rd_raw = (const float*)d_in[5];
  const float* Wdelta = (const float*)d_in[6];
  const float* Wout   = (const float*)d_in[7];
  const float* bvec   = (const float*)d_in[8];
  const float* bdelta = (const float*)d_in[9];
  const float* uh     = (const float*)d_in[10];
  const float* ud     = (const float*)d_in[11];
  float* out = (float*)d_out;
  unsigned char* ws = (unsigned char*)d_ws;

  hipMemsetAsync(ws, 0, 256, stream);                       // spectral counters/sums
  hipMemsetAsync(ws + WS_COMM, 0, 2*8192*4, stream);        // clear stale tags
  spectral_kernel<<<128, 256, 0, stream>>>(Rh_raw, Rd_raw, uh, ud, ws);
  // ax -> out region, ad -> h_lin region (dead-aliased scratch)
  gemm_f16<<<dim3(16,128), 256, 0, stream>>>(x, Rx, Wdelta, bvec, bdelta,
                                             out + OUT_OFF, out + HLIN_OFF);
  init_rows<<<32, 256, 0, stream>>>(logh0, signh0, out);
  recurrence_kernel<<<NWG, 256, 0, stream>>>(Rh_raw, Rd_raw, logh0, signh0, out, ws);
  // Y = h_lin @ W_out^T -> out region (ax dead)
  gemm_f16<<<dim3(16,128), 256, 0, stream>>>(out + HLIN_OFF, Wout, nullptr, nullptr, nullptr,
                                             out + OUT_OFF, nullptr);
  out_epilogue<<<8192, 256, 0, stream>>>(out + HLIN_OFF, out + OUT_OFF);
}

// Round 3
// 6221.261 us; speedup vs baseline: 2.0709x; 1.1618x over previous
//
#include <hip/hip_runtime.h>
#include <hip/hip_fp16.h>

#define DD 1024
#define TSTEPS 1024
#define BATCH 8
#define NWG 64
#define ROWS 16
#define HFS 1028   // LDS hf row stride in halves (514 dwords, 514%32=2 -> conflict-free-ish)

typedef _Float16 half8 __attribute__((ext_vector_type(8)));
typedef float floatx4 __attribute__((ext_vector_type(4)));

// ---- d_out float offsets ----
#define OUT_OFF   0
#define LOGH_OFF  8388608
#define SIGNH_OFF 16785408
#define HLIN_OFF  25182208

// ---- ws byte offsets ----
#define WS_SCALES  0          // float[2]
#define WS_SUMSQ   64         // float[2][8]
#define WS_FLAGS   128        // int[64]  recurrence per-WG monotonic flags -> [128,384)
#define WS_CNTS    384        // int[2][8] spectral barriers -> [384,448)
#define WS_SPECVEC 512        // float[2][2][1024] power-iter ping-pong -> [512,16896)
#define WS_COMM    16896      // ushort[2][8][1024] packed f16 h double-buffer -> [16896,49664)

__device__ __forceinline__ int aload_i(int* p) { return __hip_atomic_load(p, __ATOMIC_RELAXED, __HIP_MEMORY_SCOPE_AGENT); }
__device__ __forceinline__ float aload_f(float* p) { return __hip_atomic_load(p, __ATOMIC_RELAXED, __HIP_MEMORY_SCOPE_AGENT); }
__device__ __forceinline__ unsigned aload_u(unsigned* p) { return __hip_atomic_load(p, __ATOMIC_RELAXED, __HIP_MEMORY_SCOPE_AGENT); }
__device__ __forceinline__ void astore_f(float* p, float v) { __hip_atomic_store(p, v, __ATOMIC_RELAXED, __HIP_MEMORY_SCOPE_AGENT); }
__device__ __forceinline__ void astore_i(int* p, int v) { __hip_atomic_store(p, v, __ATOMIC_RELAXED, __HIP_MEMORY_SCOPE_AGENT); }
__device__ __forceinline__ void astore_u(unsigned* p, unsigned v) { __hip_atomic_store(p, v, __ATOMIC_RELAXED, __HIP_MEMORY_SCOPE_AGENT); }
__device__ __forceinline__ void aadd_i(int* p, int v) { (void)__hip_atomic_fetch_add(p, v, __ATOMIC_RELAXED, __HIP_MEMORY_SCOPE_AGENT); }
__device__ __forceinline__ void waitcnt_vm0() { asm volatile("s_waitcnt vmcnt(0)" ::: "memory"); }

// ============================================================================
// Spectral norm: 3-step power iteration for both matrices concurrently.
// ============================================================================
__global__ __launch_bounds__(256) void spectral_kernel(
    const float* __restrict__ Wh, const float* __restrict__ Wd,
    const float* __restrict__ uh, const float* __restrict__ ud,
    unsigned char* __restrict__ ws) {
  const int g  = blockIdx.x >> 6;
  const int wg = blockIdx.x & 63;
  const int tid = threadIdx.x;
  const float* W  = g ? Wd : Wh;
  const float* u0 = g ? ud : uh;
  float* scales = (float*)(ws + WS_SCALES);
  float* sumsq  = (float*)(ws + WS_SUMSQ) + g*8;
  int*   cnt    = (int*)(ws + WS_CNTS) + g*8;
  float* ubuf   = (float*)(ws + WS_SPECVEC) + g*2048;
  float* vbuf   = ubuf + 1024;

  __shared__ float xs[1024];
  __shared__ float tileW[256*17];
  __shared__ float red[16*17];

  float ss = 0.f;
  for (int i2 = tid; i2 < 1024; i2 += 256) { float x = u0[i2]; ss += x*x; }
  #pragma unroll
  for (int off = 1; off < 64; off <<= 1) ss += __shfl_xor(ss, off);
  if ((tid & 63) == 0) red[tid >> 6] = ss;
  __syncthreads();
  float inv_prev = 1.f/(sqrtf(red[0]+red[1]+red[2]+red[3]) + 1e-8f);
  __syncthreads();

  for (int p = 1; p <= 6; ++p) {
    const int colmv = p & 1;
    float* dst  = colmv ? vbuf : ubuf;
    float* srcw = colmv ? ubuf : vbuf;
    float part = 0.f;
    if (colmv) {
      const int jb = wg*16;
      const int jl = tid & 15, is = tid >> 4;
      float acc = 0.f;
      for (int i0 = 0; i0 < 1024; i0 += 256) {
        __syncthreads();
        float xv = (p == 1) ? u0[i0 + tid] : aload_f(srcw + i0 + tid);
        xs[tid] = xv * inv_prev;
        const float* wr = W + (size_t)(i0 + tid)*DD + jb;
        float4 a = *(const float4*)(wr + 0);
        float4 bq = *(const float4*)(wr + 4);
        float4 cq = *(const float4*)(wr + 8);
        float4 dq = *(const float4*)(wr + 12);
        float* tr = tileW + tid*17;
        tr[0]=a.x; tr[1]=a.y; tr[2]=a.z; tr[3]=a.w;
        tr[4]=bq.x; tr[5]=bq.y; tr[6]=bq.z; tr[7]=bq.w;
        tr[8]=cq.x; tr[9]=cq.y; tr[10]=cq.z; tr[11]=cq.w;
        tr[12]=dq.x; tr[13]=dq.y; tr[14]=dq.z; tr[15]=dq.w;
        __syncthreads();
        #pragma unroll 4
        for (int ii = 0; ii < 16; ++ii)
          acc += tileW[(is*16 + ii)*17 + jl] * xs[is*16 + ii];
      }
      __syncthreads();
      red[is*17 + jl] = acc;
      __syncthreads();
      if (tid < 16) {
        float y = 0.f;
        #pragma unroll
        for (int k = 0; k < 16; ++k) y += red[k*17 + tid];
        astore_f(dst + jb + tid, y);
        part = y*y;
      }
    } else {
      const int ib = wg*16;
      for (int i2 = tid; i2 < 1024; i2 += 256) xs[i2] = aload_f(srcw + i2) * inv_prev;
      __syncthreads();
      const int r = tid >> 4, s = tid & 15;
      const float* wr = W + (size_t)(ib + r)*DD;
      float acc = 0.f;
      #pragma unroll 8
      for (int jj = 0; jj < 64; ++jj) {
        int j = s + (jj << 4);
        acc += wr[j] * xs[j];
      }
      #pragma unroll
      for (int off = 1; off < 16; off <<= 1) acc += __shfl_xor(acc, off);
      __syncthreads();
      if (s == 0) red[r] = acc;
      __syncthreads();
      if (tid < 16) {
        float y = red[tid];
        astore_f(dst + ib + tid, y);
        part = y*y;
      }
    }
    #pragma unroll
    for (int off = 1; off < 16; off <<= 1) part += __shfl_xor(part, off);
    if (tid == 0) atomicAdd(sumsq + p, part);
    waitcnt_vm0();
    __syncthreads();
    if (tid == 0) {
      aadd_i(cnt + p, 1);
      while (aload_i(cnt + p) < 64) __builtin_amdgcn_s_sleep(1);
    }
    __syncthreads();
    float stot = aload_f(sumsq + p);
    inv_prev = 1.f/(sqrtf(stot) + 1e-8f);
    __syncthreads();
  }
  if (wg == 0 && tid == 0) {
    float n2 = aload_f(sumsq + 6);
    float nn = sqrtf(n2);
    float sigma = (nn*nn)/(nn + 1e-8f);
    scales[g] = 0.99f/(sigma + 1e-8f);
  }
}

// ============================================================================
// f16 MFMA GEMM (dual-B variant shares the A tile). M=8192, N=K=1024.
// ============================================================================
__device__ __forceinline__ half8 cvt8(const float* p) {
  float4 lo = *(const float4*)p;
  float4 hi = *(const float4*)(p+4);
  half8 h;
  h[0]=(_Float16)lo.x; h[1]=(_Float16)lo.y; h[2]=(_Float16)lo.z; h[3]=(_Float16)lo.w;
  h[4]=(_Float16)hi.x; h[5]=(_Float16)hi.y; h[6]=(_Float16)hi.z; h[7]=(_Float16)hi.w;
  return h;
}

__global__ __launch_bounds__(256) void gemm_f16(
    const float* __restrict__ A,
    const float* __restrict__ B1, const float* __restrict__ B2,
    const float* __restrict__ bias1, const float* __restrict__ bias2,
    float* __restrict__ C1, float* __restrict__ C2) {
  const int n0 = blockIdx.x * 64;
  const int m0 = blockIdx.y * 64;
  const int tid = threadIdx.x;
  const int wave = tid >> 6, lane = tid & 63;
  const int quad = lane >> 4, l16 = lane & 15;
  const bool dual = (B2 != nullptr);
  __shared__ _Float16 As[64*40];
  __shared__ _Float16 Bs1[64*40];
  __shared__ _Float16 Bs2[64*40];
  floatx4 zero = {0.f,0.f,0.f,0.f};
  floatx4 acc1[2][2] = {{zero,zero},{zero,zero}};
  floatx4 acc2[2][2] = {{zero,zero},{zero,zero}};
  const int srow = tid >> 2;
  const int sseg = (tid & 3) * 8;
  const int mb = (wave >> 1)*32, nb = (wave & 1)*32;
  for (int k0 = 0; k0 < 1024; k0 += 32) {
    __syncthreads();
    *(half8*)&As[srow*40 + sseg]  = cvt8(A  + (size_t)(m0+srow)*DD + k0 + sseg);
    *(half8*)&Bs1[srow*40 + sseg] = cvt8(B1 + (size_t)(n0+srow)*DD + k0 + sseg);
    if (dual) *(half8*)&Bs2[srow*40 + sseg] = cvt8(B2 + (size_t)(n0+srow)*DD + k0 + sseg);
    __syncthreads();
    half8 a0 = *(const half8*)&As[(mb + l16)*40 + quad*8];
    half8 a1 = *(const half8*)&As[(mb + 16 + l16)*40 + quad*8];
    half8 b0 = *(const half8*)&Bs1[(nb + l16)*40 + quad*8];
    half8 b1 = *(const half8*)&Bs1[(nb + 16 + l16)*40 + quad*8];
    acc1[0][0] = __builtin_amdgcn_mfma_f32_16x16x32_f16(a0, b0, acc1[0][0], 0,0,0);
    acc1[0][1] = __builtin_amdgcn_mfma_f32_16x16x32_f16(a0, b1, acc1[0][1], 0,0,0);
    acc1[1][0] = __builtin_amdgcn_mfma_f32_16x16x32_f16(a1, b0, acc1[1][0], 0,0,0);
    acc1[1][1] = __builtin_amdgcn_mfma_f32_16x16x32_f16(a1, b1, acc1[1][1], 0,0,0);
    if (dual) {
      half8 c0 = *(const half8*)&Bs2[(nb + l16)*40 + quad*8];
      half8 c1 = *(const half8*)&Bs2[(nb + 16 + l16)*40 + quad*8];
      acc2[0][0] = __builtin_amdgcn_mfma_f32_16x16x32_f16(a0, c0, acc2[0][0], 0,0,0);
      acc2[0][1] = __builtin_amdgcn_mfma_f32_16x16x32_f16(a0, c1, acc2[0][1], 0,0,0);
      acc2[1][0] = __builtin_amdgcn_mfma_f32_16x16x32_f16(a1, c0, acc2[1][0], 0,0,0);
      acc2[1][1] = __builtin_amdgcn_mfma_f32_16x16x32_f16(a1, c1, acc2[1][1], 0,0,0);
    }
  }
  #pragma unroll
  for (int in = 0; in < 2; ++in) {
    const int n = n0 + nb + in*16 + l16;
    const float bv1 = bias1 ? bias1[n] : 0.f;
    const float bv2 = (dual && bias2) ? bias2[n] : 0.f;
    #pragma unroll
    for (int im = 0; im < 2; ++im) {
      const int mrow = m0 + mb + im*16 + quad*4;
      floatx4 c = acc1[im][in];
      #pragma unroll
      for (int r2 = 0; r2 < 4; ++r2) C1[(size_t)(mrow + r2)*DD + n] = c[r2] + bv1;
      if (dual) {
        floatx4 c2 = acc2[im][in];
        #pragma unroll
        for (int r2 = 0; r2 < 4; ++r2) C2[(size_t)(mrow + r2)*DD + n] = c2[r2] + bv2;
      }
    }
  }
}

// ============================================================================
// Persistent recurrence, flag-synced:
// 64 WGs x 256 thr; WG owns 16 rows; weights register-resident as MFMA A-frags.
// Producer: payload (256 B packed f16, one coalesced store) -> vmcnt(0) ->
// flags[wg]=t+1 (agent release). Consumer: wave0 polls the 64-int flag array
// (coalesced), then all threads bulk-read the 16 KB payload (16 coalesced
// agent dword loads) into LDS. Double-buffer safety follows from flag order.
// ============================================================================
__global__ __launch_bounds__(256, 1) void recurrence_kernel(
    const float* __restrict__ Rh_raw, const float* __restrict__ Rd_raw,
    const float* __restrict__ logh0, const float* __restrict__ signh0,
    float* __restrict__ dout, unsigned char* __restrict__ ws) {
  const int wg = blockIdx.x;
  const int i0 = wg * ROWS;
  const int tid = threadIdx.x;
  const int wave = tid >> 6, lane = tid & 63;
  const int quad = lane >> 4, l16 = lane & 15;

  float* out_ax = dout + OUT_OFF;     // ax aliased into 'out' region
  float* hlin   = dout + HLIN_OFF;    // ad aliased here (consumed per step)
  float* logh   = dout + LOGH_OFF;
  float* signh  = dout + SIGNH_OFF;
  const float* scales = (const float*)(ws + WS_SCALES);
  unsigned* comm = (unsigned*)(ws + WS_COMM);   // dwords: [2][8][512]
  int* flags = (int*)(ws + WS_FLAGS);           // int[64], monotonic

  __shared__ _Float16 hf[16*HFS];
  __shared__ floatx4 scr_v[4][64];
  __shared__ floatx4 scr_d[4][64];
  __shared__ unsigned hs[64];                   // this WG's packed payload

  // zero pad batch rows 8..15 of hf (never re-written)
  for (int idx = tid; idx < 8*HFS; idx += 256) hf[8*HFS + idx] = (_Float16)0.f;

  // static A-fragments: weights * spectral scale, f16. A[m=l16][k=quad*8+j].
  const float sh = scales[0], sd = scales[1];
  half8 afv[8], afd[8];
  {
    const float* rv = Rh_raw + (size_t)(i0 + l16)*DD;
    const float* rd = Rd_raw + (size_t)(i0 + l16)*DD;
    for (int ks = 0; ks < 8; ++ks) {
      const int kb = wave*256 + ks*32 + quad*8;
      half8 hv, hd;
      #pragma unroll
      for (int j = 0; j < 8; ++j) {
        hv[j] = (_Float16)(rv[kb + j] * sh);
        hd[j] = (_Float16)(rd[kb + j] * sd);
      }
      afv[ks] = hv; afd[ks] = hd;
    }
  }

  // epilogue identity: tid<128 -> (row em, batch eb)
  const int em = tid & 15;
  const int eb = tid >> 4;
  const bool ep = (tid < 128);
  const int ei = i0 + em;
  float hp = 0.f;
  if (ep) hp = signh0[eb*DD + ei] * expf(logh0[eb*DD + ei]);

  __syncthreads();

  for (int t = 0; t < TSTEPS; ++t) {
    // prefetch ax/ad (HBM latency hidden under the poll)
    float axv = 0.f, adv = 0.f;
    if (ep) {
      axv = out_ax[(size_t)(t*8 + eb)*DD + ei];
      adv = hlin[(size_t)(t*8 + eb)*DD + ei];   // ad aliased; overwritten below
    }
    float vsum = 0.f, dsum = 0.f;
    if (t > 0) {
      // phase 1: wave0 polls 64 flags (one coalesced load per round)
      if (wave == 0) {
        unsigned long long mask;
        do {
          int fv = aload_i(flags + lane);
          mask = __ballot(fv >= t);
        } while (mask != ~0ull);
      }
      __syncthreads();
      // phase 2: bulk-read payload buffer[(t-1)&1] -> LDS (coalesced)
      {
        unsigned* src = comm + ((t-1)&1)*4096;
        #pragma unroll
        for (int q = 0; q < 16; ++q) {
          int w = q*256 + tid;
          unsigned u = aload_u(src + w);
          int b2 = w >> 9;           // 512 dwords per batch row
          int k2 = w & 511;
          *(unsigned*)&hf[b2*HFS + k2*2] = u;
        }
      }
      __syncthreads();
      // phase 3: MFMA over this wave's K-slice (both matrices share B-frag)
      floatx4 av = {0.f,0.f,0.f,0.f}, ad2 = {0.f,0.f,0.f,0.f};
      const int kw = wave*256;
      #pragma unroll
      for (int ks = 0; ks < 8; ++ks) {
        half8 bfrag = *(const half8*)&hf[l16*HFS + kw + ks*32 + quad*8];
        av  = __builtin_amdgcn_mfma_f32_16x16x32_f16(afv[ks], bfrag, av,  0, 0, 0);
        ad2 = __builtin_amdgcn_mfma_f32_16x16x32_f16(afd[ks], bfrag, ad2, 0, 0, 0);
      }
      scr_v[wave][lane] = av;
      scr_d[wave][lane] = ad2;
      __syncthreads();
      if (ep) {
        // C[m][n]: lane=(m>>2)*16+n, reg=m&3
        const int rl = ((em >> 2) << 4) + eb;
        const int rr = em & 3;
        #pragma unroll
        for (int w2 = 0; w2 < 4; ++w2) {
          vsum += scr_v[w2][rl][rr];
          dsum += scr_d[w2][rl][rr];
        }
      }
    }
    // phase 4: epilogue; hn f16 -> LDS hs (outputs held back)
    float hn = 0.f, logv = 0.f, sgn = 1.f;
    if (ep) {
      float v  = axv + vsum;
      float dd = adv + dsum;
      float cand  = tanhf(v);
      float delta = 1.f/(1.f + expf(-dd));
      hn = (1.f - delta)*hp + delta*cand;
      hp = hn;
      logv = logf(fabsf(hn) + 1e-12f);
      sgn = (hn >= 0.f) ? 1.f : -1.f;
      ((unsigned short*)hs)[eb*16 + em] = __half_as_ushort(__float2half(hn));
    }
    __syncthreads();
    // phase 5: wave0 publishes payload + release flag (critical path)
    if (wave == 0) {
      const int eb2 = lane >> 3, pr = lane & 7;
      unsigned d = hs[eb2*8 + pr];
      astore_u(comm + (t&1)*4096 + eb2*512 + wg*8 + pr, d);
      waitcnt_vm0();
      if (lane == 0) astore_i(flags + wg, t + 1);
    }
    // phase 6: off-critical-path output stores
    if (ep) {
      const size_t oidx = (size_t)(t*8 + eb)*DD + ei;
      hlin[oidx] = hn;
      logh[(size_t)((t+1)*8 + eb)*DD + ei] = logv;
      signh[(size_t)((t+1)*8 + eb)*DD + ei] = sgn;
    }
  }
}

// ============================================================================
// out = softmax(h over groups of 32) * silu(h @ W_out^T), element-wise rewrite.
// ============================================================================
__global__ __launch_bounds__(256) void out_epilogue(
    const float* __restrict__ hlin, float* __restrict__ y_out) {
  const int row = blockIdx.x;          // t*8+b
  const int tid = threadIdx.x;
  const float* h = hlin + (size_t)row*DD;
  float* yo = y_out + (size_t)row*DD;
  const int e = tid*4;
  float4 hv = *(const float4*)(h + e);
  float4 yv = *(const float4*)(yo + e);
  float m = fmaxf(fmaxf(hv.x,hv.y), fmaxf(hv.z,hv.w));
  #pragma unroll
  for (int off = 1; off < 8; off <<= 1) m = fmaxf(m, __shfl_xor(m, off));
  float e0 = expf(hv.x - m), e1 = expf(hv.y - m), e2 = expf(hv.z - m), e3 = expf(hv.w - m);
  float s = e0+e1+e2+e3;
  #pragma unroll
  for (int off = 1; off < 8; off <<= 1) s += __shfl_xor(s, off);
  float inv = 1.f/s;
  float4 o;
  o.x = e0*inv * (yv.x/(1.f+expf(-yv.x)));
  o.y = e1*inv * (yv.y/(1.f+expf(-yv.y)));
  o.z = e2*inv * (yv.z/(1.f+expf(-yv.z)));
  o.w = e3*inv * (yv.w/(1.f+expf(-yv.w)));
  *(float4*)(yo + e) = o;
}

__global__ __launch_bounds__(256) void init_rows(
    const float* __restrict__ lh0, const float* __restrict__ sh0, float* __restrict__ dout) {
  int idx = blockIdx.x*256 + threadIdx.x;   // 8192
  dout[LOGH_OFF + idx]  = lh0[idx];
  dout[SIGNH_OFF + idx] = sh0[idx];
}

extern "C" void kernel_launch(void* const* d_in, const int* in_sizes, int n_in,
                              void* d_out, int out_size, void* d_ws, size_t ws_size,
                              hipStream_t stream) {
  const float* x      = (const float*)d_in[0];
  const float* logh0  = (const float*)d_in[1];
  const float* signh0 = (const float*)d_in[2];
  const float* Rh_raw = (const float*)d_in[3];
  const float* Rx     = (const float*)d_in[4];
  const float* Rd_raw = (const float*)d_in[5];
  const float* Wdelta = (const float*)d_in[6];
  const float* Wout   = (const float*)d_in[7];
  const float* bvec   = (const float*)d_in[8];
  const float* bdelta = (const float*)d_in[9];
  const float* uh     = (const float*)d_in[10];
  const float* ud     = (const float*)d_in[11];
  float* out = (float*)d_out;
  unsigned char* ws = (unsigned char*)d_ws;

  hipMemsetAsync(ws, 0, 512, stream);   // scales/sumsq/flags/cnts
  spectral_kernel<<<128, 256, 0, stream>>>(Rh_raw, Rd_raw, uh, ud, ws);
  // ax -> out region, ad -> h_lin region (dead-aliased scratch)
  gemm_f16<<<dim3(16,128), 256, 0, stream>>>(x, Rx, Wdelta, bvec, bdelta,
                                             out + OUT_OFF, out + HLIN_OFF);
  init_rows<<<32, 256, 0, stream>>>(logh0, signh0, out);
  recurrence_kernel<<<NWG, 256, 0, stream>>>(Rh_raw, Rd_raw, logh0, signh0, out, ws);
  // Y = h_lin @ W_out^T -> out region (ax dead)
  gemm_f16<<<dim3(16,128), 256, 0, stream>>>(out + HLIN_OFF, Wout, nullptr, nullptr, nullptr,
                                             out + OUT_OFF, nullptr);
  out_epilogue<<<8192, 256, 0, stream>>>(out + HLIN_OFF, out + OUT_OFF);
}